// Round 5
// baseline (152.396 us; speedup 1.0000x reference)
//
#include <hip/hip_runtime.h>

#define BATCH 32768
#define DIM   256
#define NEXP  8
#define MT    32          // rows per tile
#define STRIDE 264        // DIM + 8 bf16 pad (measured 0 bank conflicts)

typedef __bf16 bf16x8 __attribute__((ext_vector_type(8)));
typedef __bf16 bf16x4 __attribute__((ext_vector_type(4)));
typedef float  f32x16 __attribute__((ext_vector_type(16)));

static __device__ __forceinline__ float sigmoid_f(float x) {
    return __builtin_amdgcn_rcpf(1.f + __expf(-x));
}
static __device__ __forceinline__ float tanh_f(float x) {
    return 1.f - 2.f * __builtin_amdgcn_rcpf(__expf(2.f * x) + 1.f);
}

// ---- fused prep.
// Blocks 0..255: pack W1/W2 fp32->bf16 into MFMA-B-fragment order.
// COALESCED READS (src = tid*8 consecutive floats), scattered 16B writes
// (stores don't stall the wave; gathered loads do — R4's pack had the
// gather on the load side).
// Layout (bf16x8 units): dst = [e][nt][ks][kh*32+nl], value j = W[e][nt*32+nl][ks*16+kh*8+j]
// Blocks 256..383: scatter sample indices into per-expert regions.
__global__ void prep_kernel(const float* __restrict__ W1, const float* __restrict__ W2,
                            const float* __restrict__ t,
                            bf16x8* __restrict__ W1p, bf16x8* __restrict__ W2p,
                            int* __restrict__ cursor, int* __restrict__ idxb) {
    const int b = blockIdx.x;
    if (b < 256) {
        const int tid = b * 256 + threadIdx.x;   // = e*8192 + col*32 + ks*2 + kh
        const int kh  = tid & 1;
        const int ks  = (tid >> 1) & 15;
        const int col = (tid >> 5) & 255;
        const int e   = tid >> 13;
        const long src = (long)tid * 8;          // consecutive floats -> coalesced
        const float4 a0 = *(const float4*)(W1 + src);
        const float4 a1 = *(const float4*)(W1 + src + 4);
        const float4 c0 = *(const float4*)(W2 + src);
        const float4 c1 = *(const float4*)(W2 + src + 4);
        bf16x8 w1, w2;
        w1[0] = (__bf16)a0.x; w1[1] = (__bf16)a0.y; w1[2] = (__bf16)a0.z; w1[3] = (__bf16)a0.w;
        w1[4] = (__bf16)a1.x; w1[5] = (__bf16)a1.y; w1[6] = (__bf16)a1.z; w1[7] = (__bf16)a1.w;
        w2[0] = (__bf16)c0.x; w2[1] = (__bf16)c0.y; w2[2] = (__bf16)c0.z; w2[3] = (__bf16)c0.w;
        w2[4] = (__bf16)c1.x; w2[5] = (__bf16)c1.y; w2[6] = (__bf16)c1.z; w2[7] = (__bf16)c1.w;
        const int dst = (e << 13) | ((col >> 5) << 10) | (ks << 6) | (kh << 5) | (col & 31);
        W1p[dst] = w1;
        W2p[dst] = w2;
    } else {
        __shared__ int h[NEXP], base[NEXP];
        if (threadIdx.x < NEXP) h[threadIdx.x] = 0;
        __syncthreads();
        const int i = (b - 256) * 256 + threadIdx.x;
        const int e = min((int)(t[i] * 8.0f), NEXP - 1);
        const int lr = atomicAdd(&h[e], 1);
        __syncthreads();
        if (threadIdx.x < NEXP)
            base[threadIdx.x] = atomicAdd(&cursor[threadIdx.x], h[threadIdx.x]);
        __syncthreads();
        idxb[e * BATCH + base[e] + lr] = i;
    }
}

// ---- grouped fused 2-layer MLP, software-pipelined, 2 barriers/tile.
// ab: input tile (GEMM1 A). ht: tanh output (GEMM2 A) — separate buffer so
// GEMM1->tanh needs no barrier, and next tile's staging lands in ab right
// after barrier (c) while GEMM2 reads ht.
__global__ void __launch_bounds__(256, 2)
mlp_kernel(const float* __restrict__ y,
           const float* __restrict__ scales,
           const float* __restrict__ shifta,
           const float* __restrict__ shiftb,
           const float* __restrict__ b1,
           const float* __restrict__ b2,
           const bf16x8* __restrict__ W1p,
           const bf16x8* __restrict__ W2p,
           const int* __restrict__ cnt,
           const int* __restrict__ idxb,
           float* __restrict__ out) {
    __shared__ __bf16 ab[MT * STRIDE];
    __shared__ __bf16 ht[MT * STRIDE];
    __shared__ int rows[2][MT];

    const int tx   = threadIdx.x;
    const int wave = tx >> 6;
    const int lane = tx & 63;
    const int nl   = lane & 31;
    const int kh   = lane >> 5;
    const int nbase = wave * 64;

    int c[NEXP], tp[NEXP + 1];
    tp[0] = 0;
#pragma unroll
    for (int e = 0; e < NEXP; ++e) {
        c[e] = cnt[e];
        tp[e + 1] = tp[e] + ((c[e] + MT - 1) >> 5);
    }
    const int total = tp[NEXP];

    const float sa = sigmoid_f(shifta[0]);
    const float sb = sigmoid_f(shiftb[0]);
    const float av = -sa;
    const float bvv = sb;
    const float k1 = 0.5f * (bvv - av);
    const float k2 = 0.5f * (av + bvv);
    const bool needy = (k2 != 0.0f);    // with given inputs k2==0 exactly

    int tile = blockIdx.x;
    if (tile >= total) return;

    auto get_ctx = [&](int tl, int& e_, int& rb_, int& nr_) {
        int e = 0;
#pragma unroll
        for (int j = 0; j < NEXP; ++j) if (tl >= tp[j + 1]) e = j + 1;
        e_  = e;
        rb_ = (tl - tp[e]) * MT;
        nr_ = min(MT, c[e] - rb_);
    };

    int e, rbase, nrows;
    get_ctx(tile, e, rbase, nrows);

    // ---- prologue: stage first tile into ab / rows[0]
    {
        const int* idx_e = idxb + e * BATCH;
#pragma unroll
        for (int p = 0; p < 8; ++p) {
            const int r  = p * 4 + wave;
            const int rr = min(r, nrows - 1);
            const int g  = idx_e[rbase + rr];
            if (lane == 0) rows[0][r] = (r < nrows) ? g : -1;
            const float4 v = *(const float4*)(y + (long)g * DIM + lane * 4);
            bf16x4 w;
            w[0] = (__bf16)v.x; w[1] = (__bf16)v.y; w[2] = (__bf16)v.z; w[3] = (__bf16)v.w;
            *(bf16x4*)(ab + r * STRIDE + lane * 4) = w;
        }
    }

    int cb = 0;
    while (true) {
        const int ntile = tile + gridDim.x;
        const bool hasn = ntile < total;
        int ne, nrbase, nnrows;
        get_ctx(hasn ? ntile : tile, ne, nrbase, nnrows);

        // ---- idx prefetch for next tile (completes under GEMM1)
        int g_pf[8];
        {
            const int* idx_n = idxb + ne * BATCH;
#pragma unroll
            for (int p = 0; p < 8; ++p) {
                const int r  = p * 4 + wave;
                const int rr = min(r, nnrows - 1);
                g_pf[p] = idx_n[nrbase + rr];
            }
        }

        __syncthreads();   // (a) ab/rows staging visible; prev epilogue LDS reads done

        const __bf16* apt = ab + nl * STRIDE + kh * 8;

        // ---- GEMM1: h = y @ W1[e]^T  (A from LDS, B packed-coalesced)
        const bf16x8* w1p = W1p + (e << 13) + ((nbase >> 5) << 10) + lane;
        f32x16 acc[2] = {};
#pragma unroll
        for (int ks = 0; ks < 16; ++ks) {
            bf16x8 a = *(const bf16x8*)(apt + ks * 16);
#pragma unroll
            for (int ni = 0; ni < 2; ++ni)
                acc[ni] = __builtin_amdgcn_mfma_f32_32x32x16_bf16(a, w1p[(ni << 10) + (ks << 6)], acc[ni], 0, 0, 0);
        }

        // ---- y-row gather for next tile (completes under tanh / GEMM2 lead-in)
        float4 v_pf[8];
#pragma unroll
        for (int p = 0; p < 8; ++p)
            v_pf[p] = *(const float4*)(y + (long)g_pf[p] * DIM + lane * 4);

        // ---- tanh(h + b1) -> ht (no barrier needed: separate buffer)
#pragma unroll
        for (int ni = 0; ni < 2; ++ni) {
            const int n = nbase + ni * 32 + nl;
            const float b1v = b1[(e << 8) | n];
#pragma unroll
            for (int r = 0; r < 16; ++r) {
                const int row = (r & 3) + ((r >> 2) << 3) + (kh << 2);
                ht[row * STRIDE + n] = (__bf16)tanh_f(acc[ni][r] + b1v);
            }
        }

        __syncthreads();   // (c) ht visible; all GEMM1 ds_reads of ab done

        // ---- stage next tile into ab / rows[cb^1] (overwrites ab, safe past (c))
#pragma unroll
        for (int p = 0; p < 8; ++p) {
            const int r = p * 4 + wave;
            if (lane == 0) rows[cb ^ 1][r] = (hasn && r < nnrows) ? g_pf[p] : -1;
            bf16x4 w;
            w[0] = (__bf16)v_pf[p].x; w[1] = (__bf16)v_pf[p].y;
            w[2] = (__bf16)v_pf[p].z; w[3] = (__bf16)v_pf[p].w;
            *(bf16x4*)(ab + r * STRIDE + lane * 4) = w;
        }

        // ---- GEMM2: f = h @ W2[e]^T  (A from ht)
        const __bf16* apt2 = ht + nl * STRIDE + kh * 8;
        const bf16x8* w2p = W2p + (e << 13) + ((nbase >> 5) << 10) + lane;
        f32x16 acc2[2] = {};
#pragma unroll
        for (int ks = 0; ks < 16; ++ks) {
            bf16x8 a = *(const bf16x8*)(apt2 + ks * 16);
#pragma unroll
            for (int ni = 0; ni < 2; ++ni)
                acc2[ni] = __builtin_amdgcn_mfma_f32_32x32x16_bf16(a, w2p[(ni << 10) + (ks << 6)], acc2[ni], 0, 0, 0);
        }

        // ---- epilogue: out = k1*sig(scales)*(f+b2) + k2*y
#pragma unroll
        for (int ni = 0; ni < 2; ++ni) {
            const int n = nbase + ni * 32 + nl;
            const float c1  = k1 * sigmoid_f(scales[n]);
            const float b2v = b2[(e << 8) | n];
#pragma unroll
            for (int r = 0; r < 16; ++r) {
                const int row = (r & 3) + ((r >> 2) << 3) + (kh << 2);
                const int g = rows[cb][row];
                if (g >= 0) {
                    float res = c1 * (acc2[ni][r] + b2v);
                    if (needy) res += k2 * y[(long)g * DIM + n];
                    out[(long)g * DIM + n] = res;
                }
            }
        }

        if (!hasn) break;
        tile = ntile; e = ne; rbase = nrbase; nrows = nnrows; cb ^= 1;
    }
}

extern "C" void kernel_launch(void* const* d_in, const int* in_sizes, int n_in,
                              void* d_out, int out_size, void* d_ws, size_t ws_size,
                              hipStream_t stream) {
    const float* t      = (const float*)d_in[0];
    const float* y      = (const float*)d_in[1];
    const float* W1     = (const float*)d_in[2];
    const float* b1     = (const float*)d_in[3];
    const float* W2     = (const float*)d_in[4];
    const float* b2     = (const float*)d_in[5];
    const float* scales = (const float*)d_in[6];
    const float* shifta = (const float*)d_in[7];
    const float* shiftb = (const float*)d_in[8];
    float* out = (float*)d_out;

    char* ws = (char*)d_ws;
    int* cursor = (int*)ws;                               // [8]
    int* idxb   = (int*)(ws + 256);                       // [8][32768]
    bf16x8* W1p = (bf16x8*)(ws + 256 + NEXP * BATCH * 4); // packed 1MB
    bf16x8* W2p = W1p + 65536;

    hipMemsetAsync(cursor, 0, 32, stream);
    prep_kernel<<<384, 256, 0, stream>>>(W1, W2, t, W1p, W2p, cursor, idxb);
    mlp_kernel<<<512, 256, 0, stream>>>(y, scales, shifta, shiftb, b1, b2,
                                        W1p, W2p, cursor, idxb, out);
}

// Round 6
// 138.217 us; speedup vs baseline: 1.1026x; 1.1026x over previous
//
#include <hip/hip_runtime.h>

#define BATCH 32768
#define DIM   256
#define NEXP  8
#define MT    64          // rows per tile (wave tile: 64 rows x 64 cols)
#define STRIDE 264        // DIM + 8 bf16 pad (measured 0 bank conflicts)

typedef __bf16 bf16x8 __attribute__((ext_vector_type(8)));
typedef __bf16 bf16x4 __attribute__((ext_vector_type(4)));
typedef float  f32x16 __attribute__((ext_vector_type(16)));

static __device__ __forceinline__ float sigmoid_f(float x) {
    return __builtin_amdgcn_rcpf(1.f + __expf(-x));
}
static __device__ __forceinline__ float tanh_f(float x) {
    return 1.f - 2.f * __builtin_amdgcn_rcpf(__expf(2.f * x) + 1.f);
}

// ---- fused prep.
// Blocks 0..255: pack W1/W2 fp32->bf16 into MFMA-B-fragment order.
// Coalesced reads (src = tid*8 consecutive floats), scattered 16B writes.
// Layout (bf16x8 units): dst = [e][nt][ks][kh*32+nl], value j = W[e][nt*32+nl][ks*16+kh*8+j]
// Blocks 256..383: scatter sample indices into per-expert regions.
__global__ void prep_kernel(const float* __restrict__ W1, const float* __restrict__ W2,
                            const float* __restrict__ t,
                            bf16x8* __restrict__ W1p, bf16x8* __restrict__ W2p,
                            int* __restrict__ cursor, int* __restrict__ idxb) {
    const int b = blockIdx.x;
    if (b < 256) {
        const int tid = b * 256 + threadIdx.x;   // = e*8192 + col*32 + ks*2 + kh
        const int kh  = tid & 1;
        const int ks  = (tid >> 1) & 15;
        const int col = (tid >> 5) & 255;
        const int e   = tid >> 13;
        const long src = (long)tid * 8;          // consecutive floats -> coalesced
        const float4 a0 = *(const float4*)(W1 + src);
        const float4 a1 = *(const float4*)(W1 + src + 4);
        const float4 c0 = *(const float4*)(W2 + src);
        const float4 c1 = *(const float4*)(W2 + src + 4);
        bf16x8 w1, w2;
        w1[0] = (__bf16)a0.x; w1[1] = (__bf16)a0.y; w1[2] = (__bf16)a0.z; w1[3] = (__bf16)a0.w;
        w1[4] = (__bf16)a1.x; w1[5] = (__bf16)a1.y; w1[6] = (__bf16)a1.z; w1[7] = (__bf16)a1.w;
        w2[0] = (__bf16)c0.x; w2[1] = (__bf16)c0.y; w2[2] = (__bf16)c0.z; w2[3] = (__bf16)c0.w;
        w2[4] = (__bf16)c1.x; w2[5] = (__bf16)c1.y; w2[6] = (__bf16)c1.z; w2[7] = (__bf16)c1.w;
        const int dst = (e << 13) | ((col >> 5) << 10) | (ks << 6) | (kh << 5) | (col & 31);
        W1p[dst] = w1;
        W2p[dst] = w2;
    } else {
        __shared__ int h[NEXP], base[NEXP];
        if (threadIdx.x < NEXP) h[threadIdx.x] = 0;
        __syncthreads();
        const int i = (b - 256) * 256 + threadIdx.x;
        const int e = min((int)(t[i] * 8.0f), NEXP - 1);
        const int lr = atomicAdd(&h[e], 1);
        __syncthreads();
        if (threadIdx.x < NEXP)
            base[threadIdx.x] = atomicAdd(&cursor[threadIdx.x], h[threadIdx.x]);
        __syncthreads();
        idxb[e * BATCH + base[e] + lr] = i;
    }
}

// ---- grouped fused 2-layer MLP. MT=64: each wave 64 rows x 64 cols,
// acc[2][2] 32x32 tiles; B-frag loaded ONCE per (ni,ks) and reused across
// both mi halves -> 2 MFMA per B-load (R4 was 1:1). Simple 4-barrier
// structure (pipelining measured slower 3x), 4 blocks/CU.
__global__ void __launch_bounds__(256, 4)
mlp_kernel(const float* __restrict__ y,
           const float* __restrict__ scales,
           const float* __restrict__ shifta,
           const float* __restrict__ shiftb,
           const float* __restrict__ b1,
           const float* __restrict__ b2,
           const bf16x8* __restrict__ W1p,
           const bf16x8* __restrict__ W2p,
           const int* __restrict__ cnt,
           const int* __restrict__ idxb,
           float* __restrict__ out) {
    __shared__ __bf16 ab[MT * STRIDE];   // y tile (bf16), then tanh(h); 33.8 KB
    __shared__ int rows[MT];

    const int tx   = threadIdx.x;
    const int wave = tx >> 6;
    const int lane = tx & 63;
    const int nl   = lane & 31;
    const int kh   = lane >> 5;
    const int nbase = wave * 64;

    int c[NEXP], tp[NEXP + 1];
    tp[0] = 0;
#pragma unroll
    for (int e = 0; e < NEXP; ++e) {
        c[e] = cnt[e];
        tp[e + 1] = tp[e] + ((c[e] + MT - 1) >> 6);
    }
    const int total = tp[NEXP];

    const float sa = sigmoid_f(shifta[0]);
    const float sb = sigmoid_f(shiftb[0]);
    const float av = -sa;
    const float bvv = sb;
    const float k1 = 0.5f * (bvv - av);
    const float k2 = 0.5f * (av + bvv);
    const bool needy = (k2 != 0.0f);    // with given inputs k2==0 exactly

    for (int tile = blockIdx.x; tile < total; tile += gridDim.x) {
        int e = 0;
#pragma unroll
        for (int j = 0; j < NEXP; ++j) if (tile >= tp[j + 1]) e = j + 1;
        const int rbase = (tile - tp[e]) * MT;
        const int nrows = min(MT, c[e] - rbase);
        const int* idx_e = idxb + e * BATCH;

        __syncthreads();   // previous iteration's readers of ab/rows done
        // stage gathered y rows -> bf16 LDS tile; one row per wave per pass
#pragma unroll
        for (int pass = 0; pass < 16; ++pass) {
            const int r  = pass * 4 + wave;
            const int rr = min(r, nrows - 1);
            const int g  = idx_e[rbase + rr];
            if (lane == 0) rows[r] = (r < nrows) ? g : -1;
            const float4 v = *(const float4*)(y + (long)g * DIM + lane * 4);
            bf16x4 w;
            w[0] = (__bf16)v.x; w[1] = (__bf16)v.y; w[2] = (__bf16)v.z; w[3] = (__bf16)v.w;
            *(bf16x4*)(ab + r * STRIDE + lane * 4) = w;
        }
        __syncthreads();

        const __bf16* apt0 = ab + nl * STRIDE + kh * 8;          // mi=0: rows 0..31
        const __bf16* apt1 = ab + (32 + nl) * STRIDE + kh * 8;   // mi=1: rows 32..63

        // ---- GEMM1: h = y @ W1[e]^T  (A from LDS, B packed-coalesced from L2)
        const bf16x8* w1p = W1p + (e << 13) + ((nbase >> 5) << 10) + lane;
        f32x16 acc[2][2] = {};
#pragma unroll
        for (int ks = 0; ks < 16; ++ks) {
            bf16x8 a0 = *(const bf16x8*)(apt0 + ks * 16);
            bf16x8 a1 = *(const bf16x8*)(apt1 + ks * 16);
#pragma unroll
            for (int ni = 0; ni < 2; ++ni) {
                bf16x8 bb = w1p[(ni << 10) + (ks << 6)];
                acc[0][ni] = __builtin_amdgcn_mfma_f32_32x32x16_bf16(a0, bb, acc[0][ni], 0, 0, 0);
                acc[1][ni] = __builtin_amdgcn_mfma_f32_32x32x16_bf16(a1, bb, acc[1][ni], 0, 0, 0);
            }
        }
        __syncthreads();   // all GEMM1 reads of ab complete

        // ---- tanh(h + b1) -> ab (C/D: col=lane&31, row=mi*32+(r&3)+8*(r>>2)+4*kh)
#pragma unroll
        for (int ni = 0; ni < 2; ++ni) {
            const int n = nbase + ni * 32 + nl;
            const float b1v = b1[(e << 8) | n];
#pragma unroll
            for (int mi = 0; mi < 2; ++mi) {
#pragma unroll
                for (int r = 0; r < 16; ++r) {
                    const int row = mi * 32 + (r & 3) + ((r >> 2) << 3) + (kh << 2);
                    ab[row * STRIDE + n] = (__bf16)tanh_f(acc[mi][ni][r] + b1v);
                }
            }
        }
        __syncthreads();

        // ---- GEMM2: f = h @ W2[e]^T
        const bf16x8* w2p = W2p + (e << 13) + ((nbase >> 5) << 10) + lane;
        f32x16 acc2[2][2] = {};
#pragma unroll
        for (int ks = 0; ks < 16; ++ks) {
            bf16x8 a0 = *(const bf16x8*)(apt0 + ks * 16);
            bf16x8 a1 = *(const bf16x8*)(apt1 + ks * 16);
#pragma unroll
            for (int ni = 0; ni < 2; ++ni) {
                bf16x8 bb = w2p[(ni << 10) + (ks << 6)];
                acc2[0][ni] = __builtin_amdgcn_mfma_f32_32x32x16_bf16(a0, bb, acc2[0][ni], 0, 0, 0);
                acc2[1][ni] = __builtin_amdgcn_mfma_f32_32x32x16_bf16(a1, bb, acc2[1][ni], 0, 0, 0);
            }
        }

        // ---- epilogue: out = k1*sig(scales)*(f+b2) + k2*y
#pragma unroll
        for (int ni = 0; ni < 2; ++ni) {
            const int n = nbase + ni * 32 + nl;
            const float c1  = k1 * sigmoid_f(scales[n]);
            const float b2v = b2[(e << 8) | n];
#pragma unroll
            for (int mi = 0; mi < 2; ++mi) {
#pragma unroll
                for (int r = 0; r < 16; ++r) {
                    const int row = mi * 32 + (r & 3) + ((r >> 2) << 3) + (kh << 2);
                    const int g = rows[row];
                    if (g >= 0) {
                        float res = c1 * (acc2[mi][ni][r] + b2v);
                        if (needy) res += k2 * y[(long)g * DIM + n];
                        out[(long)g * DIM + n] = res;
                    }
                }
            }
        }
    }
}

extern "C" void kernel_launch(void* const* d_in, const int* in_sizes, int n_in,
                              void* d_out, int out_size, void* d_ws, size_t ws_size,
                              hipStream_t stream) {
    const float* t      = (const float*)d_in[0];
    const float* y      = (const float*)d_in[1];
    const float* W1     = (const float*)d_in[2];
    const float* b1     = (const float*)d_in[3];
    const float* W2     = (const float*)d_in[4];
    const float* b2     = (const float*)d_in[5];
    const float* scales = (const float*)d_in[6];
    const float* shifta = (const float*)d_in[7];
    const float* shiftb = (const float*)d_in[8];
    float* out = (float*)d_out;

    char* ws = (char*)d_ws;
    int* cursor = (int*)ws;                               // [8]
    int* idxb   = (int*)(ws + 256);                       // [8][32768]
    bf16x8* W1p = (bf16x8*)(ws + 256 + NEXP * BATCH * 4); // packed 1MB
    bf16x8* W2p = W1p + 65536;

    hipMemsetAsync(cursor, 0, 32, stream);
    prep_kernel<<<384, 256, 0, stream>>>(W1, W2, t, W1p, W2p, cursor, idxb);
    // max tiles = 8 + 32768/64 = 520
    mlp_kernel<<<520, 256, 0, stream>>>(y, scales, shifta, shiftb, b1, b2,
                                        W1p, W2p, cursor, idxb, out);
}

// Round 7
// 130.664 us; speedup vs baseline: 1.1663x; 1.0578x over previous
//
#include <hip/hip_runtime.h>

#define BATCH 32768
#define DIM   256
#define NEXP  8
#define MT    64          // rows per tile
#define STRIDE 264        // DIM + 8 bf16 pad (measured 0 bank conflicts)

typedef __bf16 bf16x8 __attribute__((ext_vector_type(8)));
typedef __bf16 bf16x4 __attribute__((ext_vector_type(4)));
typedef float  f32x16 __attribute__((ext_vector_type(16)));

static __device__ __forceinline__ float sigmoid_f(float x) {
    return __builtin_amdgcn_rcpf(1.f + __expf(-x));
}
static __device__ __forceinline__ float tanh_f(float x) {
    return 1.f - 2.f * __builtin_amdgcn_rcpf(__expf(2.f * x) + 1.f);
}

// ---- fused prep (unchanged from R6).
// Blocks 0..255: pack W1/W2 fp32->bf16 into MFMA-B-fragment order.
// Layout (bf16x8 units): dst = [e][nt][ks][kh*32+nl], value j = W[e][nt*32+nl][ks*16+kh*8+j]
// Blocks 256..383: scatter sample indices into per-expert regions.
__global__ void prep_kernel(const float* __restrict__ W1, const float* __restrict__ W2,
                            const float* __restrict__ t,
                            bf16x8* __restrict__ W1p, bf16x8* __restrict__ W2p,
                            int* __restrict__ cursor, int* __restrict__ idxb) {
    const int b = blockIdx.x;
    if (b < 256) {
        const int tid = b * 256 + threadIdx.x;   // = e*8192 + col*32 + ks*2 + kh
        const int kh  = tid & 1;
        const int ks  = (tid >> 1) & 15;
        const int col = (tid >> 5) & 255;
        const int e   = tid >> 13;
        const long src = (long)tid * 8;          // consecutive floats -> coalesced
        const float4 a0 = *(const float4*)(W1 + src);
        const float4 a1 = *(const float4*)(W1 + src + 4);
        const float4 c0 = *(const float4*)(W2 + src);
        const float4 c1 = *(const float4*)(W2 + src + 4);
        bf16x8 w1, w2;
        w1[0] = (__bf16)a0.x; w1[1] = (__bf16)a0.y; w1[2] = (__bf16)a0.z; w1[3] = (__bf16)a0.w;
        w1[4] = (__bf16)a1.x; w1[5] = (__bf16)a1.y; w1[6] = (__bf16)a1.z; w1[7] = (__bf16)a1.w;
        w2[0] = (__bf16)c0.x; w2[1] = (__bf16)c0.y; w2[2] = (__bf16)c0.z; w2[3] = (__bf16)c0.w;
        w2[4] = (__bf16)c1.x; w2[5] = (__bf16)c1.y; w2[6] = (__bf16)c1.z; w2[7] = (__bf16)c1.w;
        const int dst = (e << 13) | ((col >> 5) << 10) | (ks << 6) | (kh << 5) | (col & 31);
        W1p[dst] = w1;
        W2p[dst] = w2;
    } else {
        __shared__ int h[NEXP], base[NEXP];
        if (threadIdx.x < NEXP) h[threadIdx.x] = 0;
        __syncthreads();
        const int i = (b - 256) * 256 + threadIdx.x;
        const int e = min((int)(t[i] * 8.0f), NEXP - 1);
        const int lr = atomicAdd(&h[e], 1);
        __syncthreads();
        if (threadIdx.x < NEXP)
            base[threadIdx.x] = atomicAdd(&cursor[threadIdx.x], h[threadIdx.x]);
        __syncthreads();
        idxb[e * BATCH + base[e] + lr] = i;
    }
}

// ---- grouped fused 2-layer MLP. 512-thread blocks, 8 waves: each wave
// 64 rows x 32 cols (acc[2][1]). 2 blocks/CU x 8 waves = 16 waves/CU (2x R6)
// and low per-wave reg pressure (32 AGPR acc) so the scheduler can hoist
// loads. B:MFMA reuse 1:2 kept. Simple 4-barrier structure.
__global__ void __launch_bounds__(512, 4)
mlp_kernel(const float* __restrict__ y,
           const float* __restrict__ scales,
           const float* __restrict__ shifta,
           const float* __restrict__ shiftb,
           const float* __restrict__ b1,
           const float* __restrict__ b2,
           const bf16x8* __restrict__ W1p,
           const bf16x8* __restrict__ W2p,
           const int* __restrict__ cnt,
           const int* __restrict__ idxb,
           float* __restrict__ out) {
    __shared__ __bf16 ab[MT * STRIDE];   // y tile (bf16), then tanh(h); 33.8 KB
    __shared__ int rows[MT];

    const int tx   = threadIdx.x;
    const int wave = tx >> 6;     // 0..7
    const int lane = tx & 63;
    const int nl   = lane & 31;
    const int kh   = lane >> 5;
    const int ncol = wave * 32;   // this wave's 32-col slice

    int c[NEXP], tp[NEXP + 1];
    tp[0] = 0;
#pragma unroll
    for (int e = 0; e < NEXP; ++e) {
        c[e] = cnt[e];
        tp[e + 1] = tp[e] + ((c[e] + MT - 1) >> 6);
    }
    const int total = tp[NEXP];

    const float sa = sigmoid_f(shifta[0]);
    const float sb = sigmoid_f(shiftb[0]);
    const float av = -sa;
    const float bvv = sb;
    const float k1 = 0.5f * (bvv - av);
    const float k2 = 0.5f * (av + bvv);
    const bool needy = (k2 != 0.0f);    // with given inputs k2==0 exactly

    for (int tile = blockIdx.x; tile < total; tile += gridDim.x) {
        int e = 0;
#pragma unroll
        for (int j = 0; j < NEXP; ++j) if (tile >= tp[j + 1]) e = j + 1;
        const int rbase = (tile - tp[e]) * MT;
        const int nrows = min(MT, c[e] - rbase);
        const int* idx_e = idxb + e * BATCH;

        __syncthreads();   // previous iteration's readers of ab/rows done
        // stage gathered y rows -> bf16 LDS tile; one row per wave per pass
#pragma unroll
        for (int pass = 0; pass < 8; ++pass) {
            const int r  = pass * 8 + wave;
            const int rr = min(r, nrows - 1);
            const int g  = idx_e[rbase + rr];
            if (lane == 0) rows[r] = (r < nrows) ? g : -1;
            const float4 v = *(const float4*)(y + (long)g * DIM + lane * 4);
            bf16x4 w;
            w[0] = (__bf16)v.x; w[1] = (__bf16)v.y; w[2] = (__bf16)v.z; w[3] = (__bf16)v.w;
            *(bf16x4*)(ab + r * STRIDE + lane * 4) = w;
        }
        __syncthreads();

        const __bf16* apt0 = ab + nl * STRIDE + kh * 8;          // mi=0: rows 0..31
        const __bf16* apt1 = ab + (32 + nl) * STRIDE + kh * 8;   // mi=1: rows 32..63

        // ---- GEMM1: h = y @ W1[e]^T  (A from LDS, B packed-coalesced from L2)
        // frag (wave, ks): W1p[(e<<13) + (wave<<10) + (ks<<6) + lane]
        const bf16x8* w1p = W1p + (e << 13) + (wave << 10) + lane;
        f32x16 acc[2] = {};
#pragma unroll
        for (int ks = 0; ks < 16; ++ks) {
            bf16x8 a0 = *(const bf16x8*)(apt0 + ks * 16);
            bf16x8 a1 = *(const bf16x8*)(apt1 + ks * 16);
            bf16x8 bb = w1p[ks << 6];
            acc[0] = __builtin_amdgcn_mfma_f32_32x32x16_bf16(a0, bb, acc[0], 0, 0, 0);
            acc[1] = __builtin_amdgcn_mfma_f32_32x32x16_bf16(a1, bb, acc[1], 0, 0, 0);
        }
        __syncthreads();   // all GEMM1 reads of ab complete

        // ---- tanh(h + b1) -> ab (C/D: col=nl, row=mi*32+(r&3)+8*(r>>2)+4*kh)
        {
            const int n = ncol + nl;
            const float b1v = b1[(e << 8) | n];
#pragma unroll
            for (int mi = 0; mi < 2; ++mi) {
#pragma unroll
                for (int r = 0; r < 16; ++r) {
                    const int row = mi * 32 + (r & 3) + ((r >> 2) << 3) + (kh << 2);
                    ab[row * STRIDE + n] = (__bf16)tanh_f(acc[mi][r] + b1v);
                }
            }
        }
        __syncthreads();

        // ---- GEMM2: f = h @ W2[e]^T
        const bf16x8* w2p = W2p + (e << 13) + (wave << 10) + lane;
        f32x16 acc2[2] = {};
#pragma unroll
        for (int ks = 0; ks < 16; ++ks) {
            bf16x8 a0 = *(const bf16x8*)(apt0 + ks * 16);
            bf16x8 a1 = *(const bf16x8*)(apt1 + ks * 16);
            bf16x8 bb = w2p[ks << 6];
            acc2[0] = __builtin_amdgcn_mfma_f32_32x32x16_bf16(a0, bb, acc2[0], 0, 0, 0);
            acc2[1] = __builtin_amdgcn_mfma_f32_32x32x16_bf16(a1, bb, acc2[1], 0, 0, 0);
        }

        // ---- epilogue: out = k1*sig(scales)*(f+b2) + k2*y
        {
            const int n = ncol + nl;
            const float c1  = k1 * sigmoid_f(scales[n]);
            const float b2v = b2[(e << 8) | n];
#pragma unroll
            for (int mi = 0; mi < 2; ++mi) {
#pragma unroll
                for (int r = 0; r < 16; ++r) {
                    const int row = mi * 32 + (r & 3) + ((r >> 2) << 3) + (kh << 2);
                    const int g = rows[row];
                    if (g >= 0) {
                        float res = c1 * (acc2[mi][r] + b2v);
                        if (needy) res += k2 * y[(long)g * DIM + n];
                        out[(long)g * DIM + n] = res;
                    }
                }
            }
        }
    }
}

extern "C" void kernel_launch(void* const* d_in, const int* in_sizes, int n_in,
                              void* d_out, int out_size, void* d_ws, size_t ws_size,
                              hipStream_t stream) {
    const float* t      = (const float*)d_in[0];
    const float* y      = (const float*)d_in[1];
    const float* W1     = (const float*)d_in[2];
    const float* b1     = (const float*)d_in[3];
    const float* W2     = (const float*)d_in[4];
    const float* b2     = (const float*)d_in[5];
    const float* scales = (const float*)d_in[6];
    const float* shifta = (const float*)d_in[7];
    const float* shiftb = (const float*)d_in[8];
    float* out = (float*)d_out;

    char* ws = (char*)d_ws;
    int* cursor = (int*)ws;                               // [8]
    int* idxb   = (int*)(ws + 256);                       // [8][32768]
    bf16x8* W1p = (bf16x8*)(ws + 256 + NEXP * BATCH * 4); // packed 1MB
    bf16x8* W2p = W1p + 65536;

    hipMemsetAsync(cursor, 0, 32, stream);
    prep_kernel<<<384, 256, 0, stream>>>(W1, W2, t, W1p, W2p, cursor, idxb);
    // max tiles = 8 + 32768/64 = 520
    mlp_kernel<<<520, 512, 0, stream>>>(y, scales, shifta, shiftb, b1, b2,
                                        W1p, W2p, cursor, idxb, out);
}